// Round 1
// baseline (17356.438 us; speedup 1.0000x reference)
//
#include <hip/hip_runtime.h>
#include <hip/hip_cooperative_groups.h>
#include <math.h>

namespace cg = cooperative_groups;

#define NB 128      // batch
#define NT 64       // timesteps
#define NI 512      // input dim
#define NH 1024     // hidden dim
#define NO 512      // output dim
#define PONDOFF (NB*NT*NO)

// Cooperative persistent kernel: 256 blocks x 256 threads (1 block/CU).
// Step matmul partition: 8 b-tiles (16 rows) x 32 j-slices (32 cols).
// Each thread: 1 row x 2 consecutive cols (float2 weight loads, broadcast h loads).
__global__ void __launch_bounds__(256, 1)
arnn_coop(const float* __restrict__ x, const float* __restrict__ s0,
          const float* __restrict__ w_ih, const float* __restrict__ w_hh,
          const float* __restrict__ b_ih, const float* __restrict__ b_hh,
          const float* __restrict__ w_halt, const float* __restrict__ b_halt,
          const float* __restrict__ w_out, const float* __restrict__ b_out,
          float* __restrict__ out, float* __restrict__ ws)
{
    cg::grid_group grid = cg::this_grid();
    const int tid = threadIdx.x;
    const int bid = blockIdx.x;
    const int gid = bid * 256 + tid;

    // ws layout (floats)
    float* whhT  = ws;                    // [NH][NH]  whhT[k*NH+j] = w_hh[j][k]
    float* wihT  = whhT + NH*NH;          // [NI][NH]  wihT[i*NH+j] = w_ih[j][1+i]
    float* woT   = wihT + NI*NH;          // [NH][NO]  woT[j*NO+o]  = w_out[o][j]
    float* w0    = woT  + NH*NO;          // [NH]      w_ih[j][0]
    float* hbuf  = w0   + NH;             // [2][NB][NH] step-parity h double buffer
    float* habuf = hbuf + 2*NB*NH;        // [2][NB][NH] timestep-parity h_acc
    float* halt  = habuf+ 2*NB*NH;        // [3][NB]   rotating halt-dot accumulators

    // ---- phase 0: transpose weights, zero halt slots (ws is re-poisoned every call)
    for (int e = gid; e < NH*NH; e += 256*256) {
        int k = e >> 10, j = e & (NH-1);
        whhT[e] = w_hh[j*NH + k];
    }
    for (int e = gid; e < NI*NH; e += 256*256) {
        int i = e >> 10, j = e & (NH-1);
        wihT[e] = w_ih[j*(NI+1) + 1 + i];
    }
    for (int e = gid; e < NH*NO; e += 256*256) {
        int j = e >> 9, o = e & (NO-1);
        woT[e] = w_out[o*NH + j];
    }
    if (gid < NH)  w0[gid]   = w_ih[gid*(NI+1)];
    if (gid < 3*NB) halt[gid] = 0.0f;
    grid.sync();

    // per-block redundant copy of the (uniform) row state
    __shared__ float s_cum[NB];
    __shared__ int   s_n[NB];
    __shared__ unsigned char s_act[NB];
    __shared__ int s_cnt, s_tcnt;

    const int bt = bid >> 5;              // 0..7   b-tile
    const int js = bid & 31;              // 0..31  j-slice
    const int b  = bt*16 + (tid >> 4);    // my row
    const int j  = js*32 + (tid & 15)*2;  // my 2 cols

    const float bias0 = b_ih[j]   + b_hh[j];
    const float bias1 = b_ih[j+1] + b_hh[j+1];
    const float wh0 = w_halt[j], wh1 = w_halt[j+1];
    const float w0a = w0[j],     w0b = w0[j+1];
    const float bh  = b_halt[0];

    // epilogue mapping: 8 b-tiles x 32 o-slices of 16 cols; 1 output/thread
    const int eo = (bid & 31)*16 + (tid & 15);
    const int eb = bt*16 + (tid >> 4);
    const float bo = b_out[eo];

    int g = 0;  // global step counter (uniform across blocks) -> halt slot rotation
    for (int t = 0; t < NT; ++t) {
        float xw0a = bias0, xw0b = bias1;   // x-part of preact, reused by ponder steps
        // ---------------- main step ----------------
        {
            const float* xr = x + (b*NT + t)*NI;
            const float* wp = wihT + j;
            for (int i = 0; i < NI; i += 4) {
                const float4 xv = *(const float4*)(xr + i);
                const float2 wa = *(const float2*)(wp + (i  )*NH);
                const float2 wb = *(const float2*)(wp + (i+1)*NH);
                const float2 wc = *(const float2*)(wp + (i+2)*NH);
                const float2 wd = *(const float2*)(wp + (i+3)*NH);
                xw0a += xv.x*wa.x; xw0b += xv.x*wa.y;
                xw0a += xv.y*wb.x; xw0b += xv.y*wb.y;
                xw0a += xv.z*wc.x; xw0b += xv.z*wc.y;
                xw0a += xv.w*wd.x; xw0b += xv.w*wd.y;
            }
            float a0 = xw0a + w0a, a1 = xw0b + w0b;  // ones-column contribution
            const float* hc = (t == 0) ? (s0 + b*NH)
                                       : (habuf + ((t-1)&1)*(NB*NH) + b*NH);
            const float* wp2 = whhT + j;
            for (int k = 0; k < NH; k += 4) {
                const float4 hv = *(const float4*)(hc + k);
                const float2 wa = *(const float2*)(wp2 + (k  )*NH);
                const float2 wb = *(const float2*)(wp2 + (k+1)*NH);
                const float2 wc = *(const float2*)(wp2 + (k+2)*NH);
                const float2 wd = *(const float2*)(wp2 + (k+3)*NH);
                a0 += hv.x*wa.x; a1 += hv.x*wa.y;
                a0 += hv.y*wb.x; a1 += hv.y*wb.y;
                a0 += hv.z*wc.x; a1 += hv.z*wc.y;
                a0 += hv.w*wd.x; a1 += hv.w*wd.y;
            }
            const float h0a = tanhf(a0), h0b = tanhf(a1);
            float* hw  = hbuf + b*NH + j;                       // h slot 0
            hw[0] = h0a; hw[1] = h0b;
            float* haw = habuf + (t&1)*(NB*NH) + b*NH + j;      // h_acc := h
            haw[0] = h0a; haw[1] = h0b;
            float part = h0a*wh0 + h0b*wh1;                     // halt-dot partial
            #pragma unroll
            for (int off = 8; off; off >>= 1) part += __shfl_xor(part, off, 16);
            if ((tid & 15) == 0) atomicAdd(&halt[(g%3)*NB + b], part);
        }
        grid.sync();
        // ---------------- update after main (uniform in every block) ----------------
        bool any, tany;
        {
            if (tid == 0) { s_cnt = 0; s_tcnt = 0; }
            __syncthreads();
            if (tid < NB) {
                const float z = halt[(g%3)*NB + tid] + bh;
                const float p = 1.0f / (1.0f + expf(-z));
                s_cum[tid] = p;
                s_n[tid]   = 1;
                const bool a = (p < 0.99f);
                s_act[tid] = a ? 1 : 0;
                if (a) { atomicAdd(&s_cnt, 1); if ((tid >> 4) == bt) atomicAdd(&s_tcnt, 1); }
                if (bid == 0) out[PONDOFF + tid*NT + t] = (p >= 0.99f) ? 2.0f : 0.0f;
                halt[((g+2)%3)*NB + tid] = 0.0f;   // safe slot to zero (3-slot rotation)
            }
            __syncthreads();
            any = (s_cnt > 0); tany = (s_tcnt > 0);
        }
        ++g;
        // ---------------- ponder steps ----------------
        for (int s = 1; s <= 11 && any; ++s) {
            if (tany && s_act[b]) {
                const float* hin = hbuf + ((s-1)&1)*(NB*NH) + b*NH;
                float a0 = xw0a, a1 = xw0b;     // zero-column variant: no w0 term
                const float* wp2 = whhT + j;
                for (int k = 0; k < NH; k += 4) {
                    const float4 hv = *(const float4*)(hin + k);
                    const float2 wa = *(const float2*)(wp2 + (k  )*NH);
                    const float2 wb = *(const float2*)(wp2 + (k+1)*NH);
                    const float2 wc = *(const float2*)(wp2 + (k+2)*NH);
                    const float2 wd = *(const float2*)(wp2 + (k+3)*NH);
                    a0 += hv.x*wa.x; a1 += hv.x*wa.y;
                    a0 += hv.y*wb.x; a1 += hv.y*wb.y;
                    a0 += hv.z*wc.x; a1 += hv.z*wc.y;
                    a0 += hv.w*wd.x; a1 += hv.w*wd.y;
                }
                const float hna = tanhf(a0), hnb = tanhf(a1);
                float* hw  = hbuf + (s&1)*(NB*NH) + b*NH + j;
                hw[0] = hna; hw[1] = hnb;
                float* haw = habuf + (t&1)*(NB*NH) + b*NH + j;
                haw[0] += hna; haw[1] += hnb;
                float part = hna*wh0 + hnb*wh1;
                #pragma unroll
                for (int off = 8; off; off >>= 1) part += __shfl_xor(part, off, 16);
                if ((tid & 15) == 0) atomicAdd(&halt[(g%3)*NB + b], part);
            }
            grid.sync();
            if (tid == 0) { s_cnt = 0; s_tcnt = 0; }
            __syncthreads();
            if (tid < NB) {
                if (s_act[tid]) {
                    const float z = halt[(g%3)*NB + tid] + bh;
                    const float p = 1.0f / (1.0f + expf(-z));
                    const float c = s_cum[tid] + p;
                    s_cum[tid] = c;
                    s_n[tid] += 1;
                    s_act[tid] = (c < 0.99f) ? 1 : 0;
                }
                if (s_act[tid]) { atomicAdd(&s_cnt, 1); if ((tid >> 4) == bt) atomicAdd(&s_tcnt, 1); }
                halt[((g+2)%3)*NB + tid] = 0.0f;
            }
            __syncthreads();
            any = (s_cnt > 0); tany = (s_tcnt > 0);
            ++g;
        }
        // ---------------- epilogue: out = h_acc @ W_out^T + n*b_out ----------------
        {
            const float* ha = habuf + (t&1)*(NB*NH) + eb*NH;
            const float* wq = woT + eo;
            float acc = (float)s_n[eb] * bo;
            for (int jj = 0; jj < NH; jj += 4) {
                const float4 hv = *(const float4*)(ha + jj);
                acc += hv.x * wq[(jj  )*NO];
                acc += hv.y * wq[(jj+1)*NO];
                acc += hv.z * wq[(jj+2)*NO];
                acc += hv.w * wq[(jj+3)*NO];
            }
            out[(eb*NT + t)*NO + eo] = acc;
        }
        grid.sync();   // protects h_acc (epilogue reads) vs next main-step writes
    }
}

extern "C" void kernel_launch(void* const* d_in, const int* in_sizes, int n_in,
                              void* d_out, int out_size, void* d_ws, size_t ws_size,
                              hipStream_t stream) {
    const float* x      = (const float*)d_in[0];
    const float* s0     = (const float*)d_in[1];
    const float* w_ih   = (const float*)d_in[2];
    const float* w_hh   = (const float*)d_in[3];
    const float* b_ih   = (const float*)d_in[4];
    const float* b_hh   = (const float*)d_in[5];
    const float* w_halt = (const float*)d_in[6];
    const float* b_halt = (const float*)d_in[7];
    const float* w_out  = (const float*)d_in[8];
    const float* b_out  = (const float*)d_in[9];
    float* out = (float*)d_out;
    float* ws  = (float*)d_ws;

    void* args[] = { (void*)&x, (void*)&s0, (void*)&w_ih, (void*)&w_hh,
                     (void*)&b_ih, (void*)&b_hh, (void*)&w_halt, (void*)&b_halt,
                     (void*)&w_out, (void*)&b_out, (void*)&out, (void*)&ws };
    hipLaunchCooperativeKernel((void*)arnn_coop, dim3(256), dim3(256), args, 0, stream);
}